// Round 13
// baseline (529.735 us; speedup 1.0000x reference)
//
#include <hip/hip_runtime.h>
#include <hip/hip_cooperative_groups.h>

namespace cg = cooperative_groups;

// Focal loss (prob-space), dense [B,V] fp32 + ragged one-hot targets.
// R12: R10's best config (nt loads + block-contiguous 125 KB chunks, 2-deep,
// full 2048x256 grid) merged into ONE cooperative kernel: grid.sync, then
// block 0 reduces the 2048 double partials. Saves final dispatch + gap.
#define NT 256
#define NB 2048            // == B_: one block per row; 8 blocks/CU co-resident
#define B_ 2048
#define V_ 32000
#define T_ 20
#define CHUNK 8000         // float4s per block: 16,384,000 / 2048

typedef float vfloat4 __attribute__((ext_vector_type(4)));

__device__ __forceinline__ vfloat4 nt_load4(const vfloat4* p) {
    return __builtin_nontemporal_load(p);   // global_load_dwordx4 ... nt
}

__device__ __forceinline__ float clip_p(float p) {
    // reference clip(p, 1e-8, 1-1e-8); fp32(1-1e-8)==1.0f and src<1 ->
    // upper clip is a no-op.
    return fmaxf(p, 1e-8f);
}

// t=0: 0.75 * p^2 * (-ln(1-p)) = C0 * p^2 * log2(1-p), C0 = -0.75*ln2
__device__ __forceinline__ float loss_t0(float pc) {
    float om = 1.0f - pc;
    return -0.51986038542f * pc * pc * __builtin_amdgcn_logf(om);
}

// t=1: 0.25 * (1-p)^2 * (-ln p) = C1 * (1-p)^2 * log2(p), C1 = -0.25*ln2
__device__ __forceinline__ float loss_t1(float pc) {
    float om = 1.0f - pc;
    return -0.17328679514f * om * om * __builtin_amdgcn_logf(pc);
}

__device__ __forceinline__ float loss4_t0(vfloat4 v) {
    return loss_t0(clip_p(v.x)) + loss_t0(clip_p(v.y)) +
           loss_t0(clip_p(v.z)) + loss_t0(clip_p(v.w));
}

__device__ __forceinline__ double block_reduce_f64(double v) {
    #pragma unroll
    for (int off = 32; off > 0; off >>= 1) v += __shfl_down(v, off, 64);
    __shared__ double lds[NT / 64];
    int lane = threadIdx.x & 63;
    int wid  = threadIdx.x >> 6;
    if (lane == 0) lds[wid] = v;
    __syncthreads();
    double s = 0.0;
    if (threadIdx.x == 0) {
        #pragma unroll
        for (int w = 0; w < NT / 64; ++w) s += lds[w];
    }
    return s;
}

__global__ __launch_bounds__(NT) void focal_all(const float* __restrict__ src,
                                                const int* __restrict__ tgt,
                                                double* __restrict__ part,
                                                float* __restrict__ out) {
    double acc = 0.0;

    // --- sparse correction: thread t (< T_) handles (row=blockIdx.x, t) ---
    if (threadIdx.x < T_) {
        int row = blockIdx.x;
        const int* trow = tgt + row * T_;
        int t   = threadIdx.x;
        int idx = trow[t];
        bool first = true;               // dedupe: first occurrence wins
        for (int u = 0; u < t; ++u)
            if (trow[u] == idx) first = false;
        if (first && idx >= 0 && idx < V_) {
            float pc = clip_p(src[(long)row * V_ + idx]);
            acc = (double)(loss_t1(pc) - loss_t0(pc));
        }
    }

    // --- streaming t=0 sum over this block's contiguous 125 KB chunk ---
    const vfloat4* s4 = (const vfloat4*)src + (long)blockIdx.x * CHUNK;
    for (int k = threadIdx.x; k < CHUNK; k += 2 * NT) {
        vfloat4 v0 = nt_load4(s4 + k);
        bool two = (k + NT) < CHUNK;
        vfloat4 v1;
        if (two) v1 = nt_load4(s4 + k + NT);
        acc += (double)loss4_t0(v0);
        if (two) acc += (double)loss4_t0(v1);
    }

    double s = block_reduce_f64(acc);
    if (threadIdx.x == 0) part[blockIdx.x] = s;

    cg::this_grid().sync();

    // --- final deterministic reduction in block 0 ---
    if (blockIdx.x == 0) {
        double a2 = 0.0;
        for (int k = threadIdx.x; k < NB; k += NT) a2 += part[k];
        double s2 = block_reduce_f64(a2);
        if (threadIdx.x == 0) out[0] = (float)s2;
    }
}

extern "C" void kernel_launch(void* const* d_in, const int* in_sizes, int n_in,
                              void* d_out, int out_size, void* d_ws, size_t ws_size,
                              hipStream_t stream) {
    const float* src = (const float*)d_in[0];
    const int*   tgt = (const int*)d_in[1];
    float*       out = (float*)d_out;
    double*      part = (double*)d_ws;   // NB doubles (16 KB)

    void* args[] = { (void*)&src, (void*)&tgt, (void*)&part, (void*)&out };
    hipLaunchCooperativeKernel((void*)focal_all, dim3(NB), dim3(NT), args, 0, stream);
}

// Round 14
// 330.528 us; speedup vs baseline: 1.6027x; 1.6027x over previous
//
#include <hip/hip_runtime.h>

// Focal loss (prob-space), dense [B,V] fp32 + ragged one-hot targets.
// FINAL STRUCTURE (= R10, best measured 332.05 us):
//  - nontemporal loads (no L2/LLC allocation on the streaming miss path)
//  - block-linear partition: each block streams ONE contiguous 125 KB chunk
//  - 2-deep ILP (4-deep proven null in R11), full occupancy (2048 x 256)
//  - plain two-dispatch structure (cooperative launch throttles streaming
//    reads ~4x on gfx950 — proven in R5 AND R13; do not revisit)
#define NT 256
#define NB 2048            // == B_: one block per row for the correction
#define B_ 2048
#define V_ 32000
#define T_ 20
#define CHUNK 8000         // float4s per block: 16,384,000 / 2048

typedef float vfloat4 __attribute__((ext_vector_type(4)));

__device__ __forceinline__ vfloat4 nt_load4(const vfloat4* p) {
    return __builtin_nontemporal_load(p);   // global_load_dwordx4 ... nt
}

__device__ __forceinline__ float clip_p(float p) {
    // reference clip(p, 1e-8, 1-1e-8); fp32(1-1e-8)==1.0f and src<1 ->
    // upper clip is a no-op.
    return fmaxf(p, 1e-8f);
}

// t=0: 0.75 * p^2 * (-ln(1-p)) = C0 * p^2 * log2(1-p), C0 = -0.75*ln2
__device__ __forceinline__ float loss_t0(float pc) {
    float om = 1.0f - pc;
    return -0.51986038542f * pc * pc * __builtin_amdgcn_logf(om);
}

// t=1: 0.25 * (1-p)^2 * (-ln p) = C1 * (1-p)^2 * log2(p), C1 = -0.25*ln2
__device__ __forceinline__ float loss_t1(float pc) {
    float om = 1.0f - pc;
    return -0.17328679514f * om * om * __builtin_amdgcn_logf(pc);
}

__device__ __forceinline__ float loss4_t0(vfloat4 v) {
    return loss_t0(clip_p(v.x)) + loss_t0(clip_p(v.y)) +
           loss_t0(clip_p(v.z)) + loss_t0(clip_p(v.w));
}

__device__ __forceinline__ double block_reduce_f64(double v) {
    #pragma unroll
    for (int off = 32; off > 0; off >>= 1) v += __shfl_down(v, off, 64);
    __shared__ double lds[NT / 64];
    int lane = threadIdx.x & 63;
    int wid  = threadIdx.x >> 6;
    if (lane == 0) lds[wid] = v;
    __syncthreads();
    double s = 0.0;
    if (threadIdx.x == 0) {
        #pragma unroll
        for (int w = 0; w < NT / 64; ++w) s += lds[w];
    }
    return s;
}

// Fused: block b streams its contiguous CHUNK of src (t=0 sum, nt loads,
// 2-deep) + swaps in the t=1 term for row b's unique target indices.
__global__ __launch_bounds__(NT) void focal_fused(const float* __restrict__ src,
                                                  const int* __restrict__ tgt,
                                                  double* __restrict__ part) {
    double acc = 0.0;

    // --- sparse correction: thread t (< T_) handles (row=blockIdx.x, t) ---
    if (threadIdx.x < T_) {
        int row = blockIdx.x;
        const int* trow = tgt + row * T_;
        int t   = threadIdx.x;
        int idx = trow[t];
        bool first = true;               // dedupe: first occurrence wins
        for (int u = 0; u < t; ++u)
            if (trow[u] == idx) first = false;
        if (first && idx >= 0 && idx < V_) {
            float pc = clip_p(src[(long)row * V_ + idx]);
            acc = (double)(loss_t1(pc) - loss_t0(pc));
        }
    }

    // --- streaming t=0 sum over this block's contiguous 125 KB chunk ---
    const vfloat4* s4 = (const vfloat4*)src + (long)blockIdx.x * CHUNK;
    for (int k = threadIdx.x; k < CHUNK; k += 2 * NT) {
        vfloat4 v0 = nt_load4(s4 + k);
        bool two = (k + NT) < CHUNK;
        vfloat4 v1;
        if (two) v1 = nt_load4(s4 + k + NT);
        acc += (double)loss4_t0(v0);
        if (two) acc += (double)loss4_t0(v1);
    }

    double s = block_reduce_f64(acc);
    if (threadIdx.x == 0) part[blockIdx.x] = s;
}

// Final: deterministic reduction of 2048 partials -> fp32 scalar.
__global__ __launch_bounds__(NT) void focal_final(const double* __restrict__ part,
                                                  float* __restrict__ out) {
    double acc = 0.0;
    for (int i = threadIdx.x; i < NB; i += NT) acc += part[i];
    double s = block_reduce_f64(acc);
    if (threadIdx.x == 0) out[0] = (float)s;
}

extern "C" void kernel_launch(void* const* d_in, const int* in_sizes, int n_in,
                              void* d_out, int out_size, void* d_ws, size_t ws_size,
                              hipStream_t stream) {
    const float* src = (const float*)d_in[0];
    const int*   tgt = (const int*)d_in[1];
    float*       out = (float*)d_out;
    double*      part = (double*)d_ws;   // NB doubles (16 KB)

    focal_fused<<<NB, NT, 0, stream>>>(src, tgt, part);
    focal_final<<<1, NT, 0, stream>>>(part, out);
}